// Round 1
// baseline (4622.843 us; speedup 1.0000x reference)
//
#include <hip/hip_runtime.h>
#include <cstdint>

#define NN 100000      // nodes
#define NE 1600000     // edges
#define NG 512         // graphs
constexpr int GE = 64;   // D_EMB
constexpr int GH = 128;  // D_HID
constexpr int GO = 64;   // D_OUT

__device__ __forceinline__ void atomAddF(float* p, float v) {
#if defined(__gfx90a__) || defined(__gfx942__) || defined(__gfx950__)
    unsafeAtomicAdd(p, v);
#else
    atomicAdd(p, v);
#endif
}

// monotone float->uint encoding so unsigned atomicMax == float max
__device__ __forceinline__ unsigned encF(float f) {
    unsigned s = __float_as_uint(f);
    return (s & 0x80000000u) ? ~s : (s | 0x80000000u);
}
__device__ __forceinline__ float decF(unsigned m) {
    unsigned s = (m & 0x80000000u) ? (m ^ 0x80000000u) : ~m;
    return __uint_as_float(s);
}

__global__ void k_init_outmax(unsigned* __restrict__ om) {
    int i = blockIdx.x * blockDim.x + threadIdx.x;
    if (i < NG * GO) om[i] = 0x007FFFFFu;  // encF(-inf)
}

__global__ void k_embed(const int* __restrict__ x, const float* __restrict__ emb,
                        float* __restrict__ h0) {
    int idx = blockIdx.x * blockDim.x + threadIdx.x;
    if (idx >= NN * GE) return;
    int node = idx >> 6, d = idx & 63;
    h0[idx] = emb[x[node] * GE + d];
}

// layer-1 scatter: 16 threads/edge, float4 chunks over 64 dims; deg fused on c==0
__global__ void k_scatter1(const int* __restrict__ ei, const float* __restrict__ h0,
                           float* __restrict__ agg, float* __restrict__ deg) {
    int idx = blockIdx.x * blockDim.x + threadIdx.x;
    if (idx >= NE * 16) return;
    int e = idx >> 4, c = idx & 15;
    int src = ei[e], dst = ei[NE + e];
    const float4 v = *(const float4*)(h0 + src * GE + c * 4);
    float* a = agg + dst * GE + c * 4;
    atomAddF(a + 0, v.x);
    atomAddF(a + 1, v.y);
    atomAddF(a + 2, v.z);
    atomAddF(a + 3, v.w);
    if (c == 0) atomAddF(deg + dst, 1.0f);
}

// layer-2 scatter: 32 threads/edge over 128 dims
__global__ void k_scatter2(const int* __restrict__ ei, const float* __restrict__ h1,
                           float* __restrict__ agg) {
    int idx = blockIdx.x * blockDim.x + threadIdx.x;
    if (idx >= NE * 32) return;
    int e = idx >> 5, c = idx & 31;
    int src = ei[e], dst = ei[NE + e];
    const float4 v = *(const float4*)(h1 + src * GH + c * 4);
    float* a = agg + dst * GH + c * 4;
    atomAddF(a + 0, v.x);
    atomAddF(a + 1, v.y);
    atomAddF(a + 2, v.z);
    atomAddF(a + 3, v.w);
}

// h1 = relu(aggmean @ W1l + b1 + h0 @ W1r); W in LDS; 2 nodes per block-iter
__global__ __launch_bounds__(256) void k_sage1(
        const float* __restrict__ h0, const float* __restrict__ agg,
        const float* __restrict__ deg, const float* __restrict__ W1l,
        const float* __restrict__ b1, const float* __restrict__ W1r,
        float* __restrict__ h1) {
    __shared__ float sWl[GE * GH];     // 32 KB
    __shared__ float sWr[GE * GH];     // 32 KB
    __shared__ float snode[2][2 * GE]; // per slot: aggmean(64) | h0(64)
    for (int i = threadIdx.x; i < GE * GH; i += 256) {
        sWl[i] = W1l[i];
        sWr[i] = W1r[i];
    }
    __syncthreads();
    const int slot = threadIdx.x >> 7;   // 0..1
    const int o    = threadIdx.x & 127;  // output dim
    for (int base = blockIdx.x * 2; base < NN; base += gridDim.x * 2) {
        const int node = base + slot;  // node < NN since NN even
        {
            float rinv = 1.0f / fmaxf(deg[node], 1.0f);
            snode[slot][o] = (o < GE) ? agg[node * GE + o] * rinv
                                      : h0[node * GE + (o - GE)];
        }
        __syncthreads();
        float acc = b1[o];
        #pragma unroll 8
        for (int k = 0; k < GE; ++k) {
            acc = fmaf(snode[slot][k],      sWl[k * GH + o], acc);
            acc = fmaf(snode[slot][GE + k], sWr[k * GH + o], acc);
        }
        h1[node * GH + o] = fmaxf(acc, 0.0f);
        __syncthreads();
    }
}

// h2 = aggmean @ W2l + b2 + h1 @ W2r, then atomicMax into per-graph out; 4 nodes/iter
__global__ __launch_bounds__(256) void k_sage2(
        const float* __restrict__ h1, const float* __restrict__ agg,
        const float* __restrict__ deg, const float* __restrict__ W2l,
        const float* __restrict__ b2, const float* __restrict__ W2r,
        const int* __restrict__ batch, unsigned* __restrict__ om) {
    __shared__ float sWl[GH * GO];      // 32 KB
    __shared__ float sWr[GH * GO];      // 32 KB
    __shared__ float snode[4][2 * GH];  // per slot: aggmean(128) | h1(128)
    for (int i = threadIdx.x; i < GH * GO; i += 256) {
        sWl[i] = W2l[i];
        sWr[i] = W2r[i];
    }
    __syncthreads();
    const int slot = threadIdx.x >> 6;  // 0..3
    const int o    = threadIdx.x & 63;  // output dim
    for (int base = blockIdx.x * 4; base < NN; base += gridDim.x * 4) {
        const int node = base + slot;  // node < NN since NN % 4 == 0
        {
            float rinv = 1.0f / fmaxf(deg[node], 1.0f);
            for (int j = o; j < GH; j += 64) {
                snode[slot][j]      = agg[node * GH + j] * rinv;
                snode[slot][GH + j] = h1[node * GH + j];
            }
        }
        __syncthreads();
        float acc = b2[o];
        #pragma unroll 8
        for (int k = 0; k < GH; ++k) {
            acc = fmaf(snode[slot][k],      sWl[k * GO + o], acc);
            acc = fmaf(snode[slot][GH + k], sWr[k * GO + o], acc);
        }
        const int g = batch[node];
        atomicMax(&om[g * GO + o], encF(acc));
        __syncthreads();
    }
}

__global__ void k_decode(const unsigned* __restrict__ om, float* __restrict__ out) {
    int i = blockIdx.x * blockDim.x + threadIdx.x;
    if (i < NG * GO) out[i] = decF(om[i]);
}

extern "C" void kernel_launch(void* const* d_in, const int* in_sizes, int n_in,
                              void* d_out, int out_size, void* d_ws, size_t ws_size,
                              hipStream_t stream) {
    const int*   x     = (const int*)d_in[0];
    const int*   ei    = (const int*)d_in[1];   // [2, NE] flat: src | dst
    const int*   batch = (const int*)d_in[2];
    // d_in[3] = edge_attr, unused by SAGEConv
    const float* emb   = (const float*)d_in[4];
    const float* W1l   = (const float*)d_in[5];
    const float* b1    = (const float*)d_in[6];
    const float* W1r   = (const float*)d_in[7];
    const float* W2l   = (const float*)d_in[8];
    const float* b2    = (const float*)d_in[9];
    const float* W2r   = (const float*)d_in[10];
    float* out = (float*)d_out;

    // workspace layout (fp32 elements); agg2 aliases [h0|agg1] (dead after sage1)
    float* h0   = (float*)d_ws;          // NN*GE
    float* agg1 = h0 + (size_t)NN * GE;  // NN*GE
    float* agg2 = h0;                    // NN*GH (union of h0+agg1)
    float* h1   = agg1 + (size_t)NN * GE; // NN*GH
    float* deg  = h1 + (size_t)NN * GH;  // NN
    unsigned* om = (unsigned*)(deg + NN); // NG*GO

    hipMemsetAsync(agg1, 0, sizeof(float) * (size_t)NN * GE, stream);
    hipMemsetAsync(deg,  0, sizeof(float) * NN, stream);
    k_init_outmax<<<(NG * GO + 255) / 256, 256, 0, stream>>>(om);

    k_embed<<<(NN * GE + 255) / 256, 256, 0, stream>>>(x, emb, h0);
    k_scatter1<<<(NE * 16 + 255) / 256, 256, 0, stream>>>(ei, h0, agg1, deg);
    k_sage1<<<2048, 256, 0, stream>>>(h0, agg1, deg, W1l, b1, W1r, h1);

    hipMemsetAsync(agg2, 0, sizeof(float) * (size_t)NN * GH, stream);
    k_scatter2<<<(NE * 32 + 255) / 256, 256, 0, stream>>>(ei, h1, agg2);
    k_sage2<<<2048, 256, 0, stream>>>(h1, agg2, deg, W2l, b2, W2r, batch, om);

    k_decode<<<(NG * GO + 255) / 256, 256, 0, stream>>>(om, out);
}

// Round 2
// 1028.777 us; speedup vs baseline: 4.4935x; 4.4935x over previous
//
#include <hip/hip_runtime.h>
#include <cstdint>

#define NN 100000      // nodes
#define NE 1600000     // edges
#define NG 512         // graphs
constexpr int GE = 64;   // D_EMB
constexpr int GH = 128;  // D_HID
constexpr int GO = 64;   // D_OUT

// monotone float->uint encoding so unsigned atomicMax == float max
__device__ __forceinline__ unsigned encF(float f) {
    unsigned s = __float_as_uint(f);
    return (s & 0x80000000u) ? ~s : (s | 0x80000000u);
}
__device__ __forceinline__ float decF(unsigned m) {
    unsigned s = (m & 0x80000000u) ? (m ^ 0x80000000u) : ~m;
    return __uint_as_float(s);
}

__global__ void k_init_outmax(unsigned* __restrict__ om) {
    int i = blockIdx.x * blockDim.x + threadIdx.x;
    if (i < NG * GO) om[i] = 0x007FFFFFu;  // encF(-inf)
}

__global__ void k_embed(const int* __restrict__ x, const float* __restrict__ emb,
                        float* __restrict__ h0) {
    int idx = blockIdx.x * blockDim.x + threadIdx.x;
    if (idx >= NN * GE) return;
    int node = idx >> 6, d = idx & 63;
    h0[idx] = emb[x[node] * GE + d];
}

// ---- CSR construction ----
__global__ void k_count(const int* __restrict__ ei, int* __restrict__ degi) {
    int e = blockIdx.x * blockDim.x + threadIdx.x;
    if (e < NE) atomicAdd(&degi[ei[NE + e]], 1);
}

// single-block exclusive scan over NN degrees -> offsets[NN+1]
__global__ __launch_bounds__(1024) void k_scan(const int* __restrict__ degi,
                                               int* __restrict__ off) {
    __shared__ int s[1024];
    const int T = 1024;
    const int chunk = (NN + T - 1) / T;  // 98
    int t = threadIdx.x;
    int lo = t * chunk, hi = min(lo + chunk, NN);
    int sum = 0;
    for (int i = lo; i < hi; ++i) sum += degi[i];
    s[t] = sum;
    __syncthreads();
    for (int d = 1; d < T; d <<= 1) {
        int v = (t >= d) ? s[t - d] : 0;
        __syncthreads();
        if (t >= d) s[t] += v;
        __syncthreads();
    }
    int run = (t == 0) ? 0 : s[t - 1];
    for (int i = lo; i < hi; ++i) {
        off[i] = run;
        run += degi[i];
    }
    if (t == T - 1) off[NN] = NE;
}

__global__ void k_fill(const int* __restrict__ ei, const int* __restrict__ off,
                       int* __restrict__ cursor, int* __restrict__ csr) {
    int e = blockIdx.x * blockDim.x + threadIdx.x;
    if (e >= NE) return;
    int src = ei[e], dst = ei[NE + e];
    int pos = off[dst] + atomicAdd(&cursor[dst], 1);
    csr[pos] = src;
}

// ---- gather-based mean aggregation (one wave per node, lane = dim) ----
__global__ __launch_bounds__(256) void k_gather1(const int* __restrict__ off,
                                                 const int* __restrict__ csr,
                                                 const float* __restrict__ h0,
                                                 float* __restrict__ agg) {
    int wid = (blockIdx.x * blockDim.x + threadIdx.x) >> 6;  // node
    int lane = threadIdx.x & 63;
    if (wid >= NN) return;
    int beg = off[wid], end = off[wid + 1];
    float acc = 0.0f;
    for (int base = beg; base < end; base += 64) {
        int n = min(64, end - base);
        int s = (lane < n) ? csr[base + lane] : 0;
        for (int j = 0; j < n; ++j) {
            int src = __builtin_amdgcn_readlane(s, j);  // wave-uniform broadcast
            acc += h0[src * GE + lane];
        }
    }
    agg[wid * GE + lane] = acc / fmaxf((float)(end - beg), 1.0f);
}

__global__ __launch_bounds__(256) void k_gather2(const int* __restrict__ off,
                                                 const int* __restrict__ csr,
                                                 const float* __restrict__ h1,
                                                 float* __restrict__ agg) {
    int wid = (blockIdx.x * blockDim.x + threadIdx.x) >> 6;  // node
    int lane = threadIdx.x & 63;
    if (wid >= NN) return;
    int beg = off[wid], end = off[wid + 1];
    float acc0 = 0.0f, acc1 = 0.0f;
    for (int base = beg; base < end; base += 64) {
        int n = min(64, end - base);
        int s = (lane < n) ? csr[base + lane] : 0;
        for (int j = 0; j < n; ++j) {
            int src = __builtin_amdgcn_readlane(s, j);
            acc0 += h1[src * GH + lane];
            acc1 += h1[src * GH + 64 + lane];
        }
    }
    float rinv = 1.0f / fmaxf((float)(end - beg), 1.0f);
    agg[wid * GH + lane] = acc0 * rinv;
    agg[wid * GH + 64 + lane] = acc1 * rinv;
}

// h1 = relu(aggmean @ W1l + b1 + h0 @ W1r); W in LDS; 2 nodes per block-iter
__global__ __launch_bounds__(256) void k_sage1(
        const float* __restrict__ h0, const float* __restrict__ agg,
        const float* __restrict__ W1l, const float* __restrict__ b1,
        const float* __restrict__ W1r, float* __restrict__ h1) {
    __shared__ float sWl[GE * GH];     // 32 KB
    __shared__ float sWr[GE * GH];     // 32 KB
    __shared__ float snode[2][2 * GE]; // per slot: aggmean(64) | h0(64)
    for (int i = threadIdx.x; i < GE * GH; i += 256) {
        sWl[i] = W1l[i];
        sWr[i] = W1r[i];
    }
    __syncthreads();
    const int slot = threadIdx.x >> 7;   // 0..1
    const int o    = threadIdx.x & 127;  // output dim
    for (int base = blockIdx.x * 2; base < NN; base += gridDim.x * 2) {
        const int node = base + slot;  // node < NN since NN even
        snode[slot][o] = (o < GE) ? agg[node * GE + o]
                                  : h0[node * GE + (o - GE)];
        __syncthreads();
        float acc = b1[o];
        #pragma unroll 8
        for (int k = 0; k < GE; ++k) {
            acc = fmaf(snode[slot][k],      sWl[k * GH + o], acc);
            acc = fmaf(snode[slot][GE + k], sWr[k * GH + o], acc);
        }
        h1[node * GH + o] = fmaxf(acc, 0.0f);
        __syncthreads();
    }
}

// h2 = aggmean @ W2l + b2 + h1 @ W2r, then atomicMax into per-graph out; 4 nodes/iter
__global__ __launch_bounds__(256) void k_sage2(
        const float* __restrict__ h1, const float* __restrict__ agg,
        const float* __restrict__ W2l, const float* __restrict__ b2,
        const float* __restrict__ W2r, const int* __restrict__ batch,
        unsigned* __restrict__ om) {
    __shared__ float sWl[GH * GO];      // 32 KB
    __shared__ float sWr[GH * GO];      // 32 KB
    __shared__ float snode[4][2 * GH];  // per slot: aggmean(128) | h1(128)
    for (int i = threadIdx.x; i < GH * GO; i += 256) {
        sWl[i] = W2l[i];
        sWr[i] = W2r[i];
    }
    __syncthreads();
    const int slot = threadIdx.x >> 6;  // 0..3
    const int o    = threadIdx.x & 63;  // output dim
    for (int base = blockIdx.x * 4; base < NN; base += gridDim.x * 4) {
        const int node = base + slot;  // node < NN since NN % 4 == 0
        for (int j = o; j < GH; j += 64) {
            snode[slot][j]      = agg[node * GH + j];
            snode[slot][GH + j] = h1[node * GH + j];
        }
        __syncthreads();
        float acc = b2[o];
        #pragma unroll 8
        for (int k = 0; k < GH; ++k) {
            acc = fmaf(snode[slot][k],      sWl[k * GO + o], acc);
            acc = fmaf(snode[slot][GH + k], sWr[k * GO + o], acc);
        }
        const int g = batch[node];
        atomicMax(&om[g * GO + o], encF(acc));
        __syncthreads();
    }
}

__global__ void k_decode(const unsigned* __restrict__ om, float* __restrict__ out) {
    int i = blockIdx.x * blockDim.x + threadIdx.x;
    if (i < NG * GO) out[i] = decF(om[i]);
}

extern "C" void kernel_launch(void* const* d_in, const int* in_sizes, int n_in,
                              void* d_out, int out_size, void* d_ws, size_t ws_size,
                              hipStream_t stream) {
    const int*   x     = (const int*)d_in[0];
    const int*   ei    = (const int*)d_in[1];   // [2, NE] flat: src | dst
    const int*   batch = (const int*)d_in[2];
    // d_in[3] = edge_attr, unused by SAGEConv
    const float* emb   = (const float*)d_in[4];
    const float* W1l   = (const float*)d_in[5];
    const float* b1    = (const float*)d_in[6];
    const float* W1r   = (const float*)d_in[7];
    const float* W2l   = (const float*)d_in[8];
    const float* b2    = (const float*)d_in[9];
    const float* W2r   = (const float*)d_in[10];
    float* out = (float*)d_out;

    // workspace layout (fp32 elements); agg2 aliases [h0|agg1] (dead after sage1)
    float* h0   = (float*)d_ws;            // NN*GE
    float* agg1 = h0 + (size_t)NN * GE;    // NN*GE
    float* agg2 = h0;                      // NN*GH (union of h0+agg1)
    float* h1   = agg1 + (size_t)NN * GE;  // NN*GH
    int*   degi = (int*)(h1 + (size_t)NN * GH);  // NN (also reused as fill cursor)
    int*   off  = degi + NN;               // NN+1
    int*   csr  = off + NN + 1;            // NE
    unsigned* om = (unsigned*)(csr + NE);  // NG*GO

    // --- CSR build (shared by both layers) ---
    hipMemsetAsync(degi, 0, sizeof(int) * NN, stream);
    k_count<<<(NE + 255) / 256, 256, 0, stream>>>(ei, degi);
    k_scan<<<1, 1024, 0, stream>>>(degi, off);
    hipMemsetAsync(degi, 0, sizeof(int) * NN, stream);  // reuse as cursor
    k_fill<<<(NE + 255) / 256, 256, 0, stream>>>(ei, off, degi, csr);

    k_init_outmax<<<(NG * GO + 255) / 256, 256, 0, stream>>>(om);
    k_embed<<<(NN * GE + 255) / 256, 256, 0, stream>>>(x, emb, h0);

    // --- layer 1 ---
    k_gather1<<<(NN * 64 + 255) / 256, 256, 0, stream>>>(off, csr, h0, agg1);
    k_sage1<<<2048, 256, 0, stream>>>(h0, agg1, W1l, b1, W1r, h1);

    // --- layer 2 ---
    k_gather2<<<(NN * 64 + 255) / 256, 256, 0, stream>>>(off, csr, h1, agg2);
    k_sage2<<<2048, 256, 0, stream>>>(h1, agg2, W2l, b2, W2r, batch, om);

    k_decode<<<(NG * GO + 255) / 256, 256, 0, stream>>>(om, out);
}

// Round 3
// 529.049 us; speedup vs baseline: 8.7380x; 1.9446x over previous
//
#include <hip/hip_runtime.h>
#include <cstdint>

#define NN 100000      // nodes
#define NE 1600000     // edges
#define NG 512         // graphs
#define NP 100032      // NN padded to 64*1563
#define NBLK 391       // ceil(NN/256) for scan kernels

typedef unsigned short u16;
typedef u16    u16x8  __attribute__((ext_vector_type(8)));
typedef __bf16 bf16x8 __attribute__((ext_vector_type(8)));
typedef float  f32x4  __attribute__((ext_vector_type(4)));

__device__ __forceinline__ u16 f2bf(float f) {  // RNE, inputs are normal floats
    unsigned u = __float_as_uint(f);
    unsigned r = ((u >> 16) & 1u) + 0x7FFFu;
    return (u16)((u + r) >> 16);
}
__device__ __forceinline__ float bf2f(u16 h) {
    return __uint_as_float(((unsigned)h) << 16);
}

// monotone float->uint encoding so unsigned atomicMax == float max
__device__ __forceinline__ unsigned encF(float f) {
    unsigned s = __float_as_uint(f);
    return (s & 0x80000000u) ? ~s : (s | 0x80000000u);
}
__device__ __forceinline__ float decF(unsigned m) {
    unsigned s = (m & 0x80000000u) ? (m ^ 0x80000000u) : ~m;
    return __uint_as_float(s);
}

__global__ void k_init_outmax(unsigned* __restrict__ om) {
    int i = blockIdx.x * blockDim.x + threadIdx.x;
    if (i < NG * 64) om[i] = 0x007FFFFFu;  // encF(-inf)
}

// embed -> bf16, stored into cols 64..127 of A1 (the "x_i" half)
__global__ void k_embed(const int* __restrict__ x, const float* __restrict__ emb,
                        u16* __restrict__ A1) {
    int idx = blockIdx.x * blockDim.x + threadIdx.x;
    if (idx >= NN * 64) return;
    int node = idx >> 6, d = idx & 63;
    A1[node * 128 + 64 + d] = f2bf(emb[x[node] * 64 + d]);
}

// ---- CSR construction ----
__global__ void k_count(const int* __restrict__ ei, int* __restrict__ degi) {
    int e = blockIdx.x * blockDim.x + threadIdx.x;
    if (e < NE) atomicAdd(&degi[ei[NE + e]], 1);
}

__global__ void k_blocksum(const int* __restrict__ degi, int* __restrict__ partial) {
    __shared__ int s[256];
    int i = blockIdx.x * 256 + threadIdx.x;
    s[threadIdx.x] = (i < NN) ? degi[i] : 0;
    __syncthreads();
    for (int d = 128; d > 0; d >>= 1) {
        if (threadIdx.x < d) s[threadIdx.x] += s[threadIdx.x + d];
        __syncthreads();
    }
    if (threadIdx.x == 0) partial[blockIdx.x] = s[0];
}

__global__ __launch_bounds__(512) void k_scanpart(const int* __restrict__ partial,
                                                  int* __restrict__ bases) {
    __shared__ int s[512];
    int t = threadIdx.x;
    s[t] = (t < NBLK) ? partial[t] : 0;
    __syncthreads();
    for (int d = 1; d < 512; d <<= 1) {
        int v = (t >= d) ? s[t - d] : 0;
        __syncthreads();
        s[t] += v;
        __syncthreads();
    }
    if (t < NBLK) bases[t] = (t == 0) ? 0 : s[t - 1];
}

__global__ void k_offsets(const int* __restrict__ degi, const int* __restrict__ bases,
                          int* __restrict__ off) {
    __shared__ int s[256];
    int t = threadIdx.x, i = blockIdx.x * 256 + t;
    int d = (i < NN) ? degi[i] : 0;
    s[t] = d;
    __syncthreads();
    for (int dd = 1; dd < 256; dd <<= 1) {
        int v = (t >= dd) ? s[t - dd] : 0;
        __syncthreads();
        s[t] += v;
        __syncthreads();
    }
    if (i < NN) off[i] = bases[blockIdx.x] + s[t] - d;  // exclusive
    if (blockIdx.x == gridDim.x - 1 && t == 255) off[NN] = NE;
}

__global__ void k_fill(const int* __restrict__ ei, const int* __restrict__ off,
                       int* __restrict__ cursor, int* __restrict__ csr) {
    int e = blockIdx.x * blockDim.x + threadIdx.x;
    if (e >= NE) return;
    int src = ei[e], dst = ei[NE + e];
    int pos = off[dst] + atomicAdd(&cursor[dst], 1);
    csr[pos] = src;
}

// ---- weight prep: fp32 concat -> bf16 packed in B-fragment order ----
// frag id fid = cTile*4 + ks; element j of lane: B[ks*32+quad*8+j][cTile*16+(lane&15)]
// mode 0: vertical stack  [Wa;Wb], Wa/Wb are [64 x 128]
// mode 1: horizontal concat [Wa|Wb], Wa/Wb are [128 x 64]
__global__ void k_prepW(const float* __restrict__ Wa, const float* __restrict__ Wb,
                        int mode, u16* __restrict__ Wpk) {
    int idx = blockIdx.x * blockDim.x + threadIdx.x;  // 0..2047
    if (idx >= 2048) return;
    int fid = idx >> 6, lane = idx & 63;
    int cT = fid >> 2, ks = fid & 3;
    int quad = lane >> 4, l16 = lane & 15;
    int n = cT * 16 + l16;
    u16x8 v;
    #pragma unroll
    for (int j = 0; j < 8; ++j) {
        int k = ks * 32 + quad * 8 + j;
        float f = (mode == 0) ? (k < 64 ? Wa[k * 128 + n] : Wb[(k - 64) * 128 + n])
                              : (n < 64 ? Wa[k * 64 + n] : Wb[k * 64 + (n - 64)]);
        v[j] = f2bf(f);
    }
    *(u16x8*)(Wpk + idx * 8) = v;
}

// ---- gather-mean of h0 (cols 64..127 of A1) into cols 0..63 of A1, bf16 ----
__global__ __launch_bounds__(256) void k_gather1(const int* __restrict__ off,
                                                 const int* __restrict__ csr,
                                                 u16* __restrict__ A1) {
    int wid = (blockIdx.x * blockDim.x + threadIdx.x) >> 6;  // node
    int lane = threadIdx.x & 63;
    if (wid >= NN) return;
    int beg = off[wid], end = off[wid + 1];
    float acc = 0.0f;
    for (int base = beg; base < end; base += 64) {
        int n = min(64, end - base);
        int s = (lane < n) ? csr[base + lane] : 0;
        for (int j = 0; j < n; ++j) {
            int src = __builtin_amdgcn_readlane(s, j);
            acc += bf2f(A1[src * 128 + 64 + lane]);
        }
    }
    float rinv = 1.0f / fmaxf((float)(end - beg), 1.0f);
    A1[wid * 128 + lane] = f2bf(acc * rinv);
}

// ---- GEMM1: H1 = relu(A1[NPx128] @ Wpk1[128x128] + b1), bf16 out ----
// block: 256 thr = 4 waves; block computes 64 rows x 128 cols; wave w owns cols w*32..w*32+31
__global__ __launch_bounds__(256) void k_gemm1(const u16* __restrict__ A1,
                                               const u16* __restrict__ Wpk,
                                               const float* __restrict__ b1,
                                               u16* __restrict__ H1) {
    int w = threadIdx.x >> 6, lane = threadIdx.x & 63;
    int quad = lane >> 4, l16 = lane & 15;
    u16x8 bfr[2][4];
    #pragma unroll
    for (int ct = 0; ct < 2; ++ct)
        #pragma unroll
        for (int ks = 0; ks < 4; ++ks) {
            int fid = (w * 2 + ct) * 4 + ks;
            bfr[ct][ks] = *(const u16x8*)(Wpk + (fid * 64 + lane) * 8);
        }
    int r0 = blockIdx.x * 64;
    #pragma unroll
    for (int rt = 0; rt < 4; ++rt) {
        int row = r0 + rt * 16 + l16;
        u16x8 a[4];
        #pragma unroll
        for (int ks = 0; ks < 4; ++ks)
            a[ks] = *(const u16x8*)(A1 + row * 128 + ks * 32 + quad * 8);
        #pragma unroll
        for (int ct = 0; ct < 2; ++ct) {
            f32x4 acc = {0.f, 0.f, 0.f, 0.f};
            #pragma unroll
            for (int ks = 0; ks < 4; ++ks)
                acc = __builtin_amdgcn_mfma_f32_16x16x32_bf16(
                    __builtin_bit_cast(bf16x8, a[ks]),
                    __builtin_bit_cast(bf16x8, bfr[ct][ks]), acc, 0, 0, 0);
            int col = w * 32 + ct * 16 + l16;
            float bias = b1[col];
            int gr = r0 + rt * 16 + quad * 4;
            #pragma unroll
            for (int reg = 0; reg < 4; ++reg)
                H1[(gr + reg) * 128 + col] = f2bf(fmaxf(acc[reg] + bias, 0.f));
        }
    }
}

// ---- GEMM2: PQ = H1[NPx128] @ Wpk2[128x128], bf16 out (p = cols 0..63, q = 64..127) ----
__global__ __launch_bounds__(256) void k_gemm2(const u16* __restrict__ H1,
                                               const u16* __restrict__ Wpk,
                                               u16* __restrict__ PQ) {
    int w = threadIdx.x >> 6, lane = threadIdx.x & 63;
    int quad = lane >> 4, l16 = lane & 15;
    u16x8 bfr[2][4];
    #pragma unroll
    for (int ct = 0; ct < 2; ++ct)
        #pragma unroll
        for (int ks = 0; ks < 4; ++ks) {
            int fid = (w * 2 + ct) * 4 + ks;
            bfr[ct][ks] = *(const u16x8*)(Wpk + (fid * 64 + lane) * 8);
        }
    int r0 = blockIdx.x * 64;
    #pragma unroll
    for (int rt = 0; rt < 4; ++rt) {
        int row = r0 + rt * 16 + l16;
        u16x8 a[4];
        #pragma unroll
        for (int ks = 0; ks < 4; ++ks)
            a[ks] = *(const u16x8*)(H1 + row * 128 + ks * 32 + quad * 8);
        #pragma unroll
        for (int ct = 0; ct < 2; ++ct) {
            f32x4 acc = {0.f, 0.f, 0.f, 0.f};
            #pragma unroll
            for (int ks = 0; ks < 4; ++ks)
                acc = __builtin_amdgcn_mfma_f32_16x16x32_bf16(
                    __builtin_bit_cast(bf16x8, a[ks]),
                    __builtin_bit_cast(bf16x8, bfr[ct][ks]), acc, 0, 0, 0);
            int col = w * 32 + ct * 16 + l16;
            int gr = r0 + rt * 16 + quad * 4;
            #pragma unroll
            for (int reg = 0; reg < 4; ++reg)
                PQ[(gr + reg) * 128 + col] = f2bf(acc[reg]);
        }
    }
}

// ---- final: h2 = mean_agg(p) + b2 + q, segment-max into om ----
// block = 4 waves = 4 consecutive nodes (batch sorted) -> pre-reduce before atomics
__global__ __launch_bounds__(256) void k_final(const int* __restrict__ off,
                                               const int* __restrict__ csr,
                                               const u16* __restrict__ PQ,
                                               const float* __restrict__ b2,
                                               const int* __restrict__ batch,
                                               unsigned* __restrict__ om) {
    __shared__ float sR[4][64];
    __shared__ int sG[4];
    int wv = threadIdx.x >> 6, lane = threadIdx.x & 63;
    int node = blockIdx.x * 4 + wv;  // NN % 4 == 0, always valid
    int beg = off[node], end = off[node + 1];
    float acc = 0.0f;
    for (int base = beg; base < end; base += 64) {
        int n = min(64, end - base);
        int s = (lane < n) ? csr[base + lane] : 0;
        for (int j = 0; j < n; ++j) {
            int src = __builtin_amdgcn_readlane(s, j);
            acc += bf2f(PQ[src * 128 + lane]);
        }
    }
    float r = acc / fmaxf((float)(end - beg), 1.0f) + b2[lane]
            + bf2f(PQ[node * 128 + 64 + lane]);
    int g = batch[node];
    sR[wv][lane] = r;
    if (lane == 0) sG[wv] = g;
    __syncthreads();
    bool leader = (wv == 0) || (sG[wv - 1] != g);
    if (leader) {
        float m = r;
        for (int u = wv + 1; u < 4 && sG[u] == g; ++u) m = fmaxf(m, sR[u][lane]);
        atomicMax(&om[g * 64 + lane], encF(m));
    }
}

__global__ void k_decode(const unsigned* __restrict__ om, float* __restrict__ out) {
    int i = blockIdx.x * blockDim.x + threadIdx.x;
    if (i < NG * 64) out[i] = decF(om[i]);
}

extern "C" void kernel_launch(void* const* d_in, const int* in_sizes, int n_in,
                              void* d_out, int out_size, void* d_ws, size_t ws_size,
                              hipStream_t stream) {
    const int*   x     = (const int*)d_in[0];
    const int*   ei    = (const int*)d_in[1];   // [2, NE] flat: src | dst
    const int*   batch = (const int*)d_in[2];
    // d_in[3] = edge_attr, unused by SAGEConv
    const float* emb   = (const float*)d_in[4];
    const float* W1l   = (const float*)d_in[5];
    const float* b1    = (const float*)d_in[6];
    const float* W1r   = (const float*)d_in[7];
    const float* W2l   = (const float*)d_in[8];
    const float* b2    = (const float*)d_in[9];
    const float* W2r   = (const float*)d_in[10];
    float* out = (float*)d_out;

    // workspace layout (bytes). bf16 tables are NP x 128.
    char* p = (char*)d_ws;
    u16* A1   = (u16*)p;               p += (size_t)NP * 128 * 2;  // [agg1 | h0]
    u16* H1   = (u16*)p;               p += (size_t)NP * 128 * 2;
    u16* PQ   = (u16*)p;               p += (size_t)NP * 128 * 2;  // [p | q]
    int* csr  = (int*)p;               p += (size_t)NE * 4;
    int* off  = (int*)p;               p += (size_t)(NN + 1) * 4;
    int* degi = (int*)p;               p += (size_t)NN * 4;        // also fill cursor
    int* part = (int*)p;               p += 512 * 4;
    int* base = (int*)p;               p += 512 * 4;
    u16* Wpk1 = (u16*)p;               p += 16384 * 2;
    u16* Wpk2 = (u16*)p;               p += 16384 * 2;
    unsigned* om = (unsigned*)p;

    // --- CSR build ---
    hipMemsetAsync(degi, 0, sizeof(int) * NN, stream);
    k_count<<<(NE + 255) / 256, 256, 0, stream>>>(ei, degi);
    k_blocksum<<<NBLK, 256, 0, stream>>>(degi, part);
    k_scanpart<<<1, 512, 0, stream>>>(part, base);
    k_offsets<<<NBLK, 256, 0, stream>>>(degi, base, off);
    hipMemsetAsync(degi, 0, sizeof(int) * NN, stream);  // reuse as cursor
    k_fill<<<(NE + 255) / 256, 256, 0, stream>>>(ei, off, degi, csr);

    // --- weight prep + init ---
    k_prepW<<<8, 256, 0, stream>>>(W1l, W1r, 0, Wpk1);  // vertical stack [W1l;W1r]
    k_prepW<<<8, 256, 0, stream>>>(W2l, W2r, 1, Wpk2);  // horizontal [W2l|W2r]
    k_init_outmax<<<(NG * 64 + 255) / 256, 256, 0, stream>>>(om);

    // --- layer 1 ---
    k_embed<<<(NN * 64 + 255) / 256, 256, 0, stream>>>(x, emb, A1);
    k_gather1<<<(NN * 64 + 255) / 256, 256, 0, stream>>>(off, csr, A1);
    k_gemm1<<<NP / 64, 256, 0, stream>>>(A1, Wpk1, b1, H1);

    // --- layer 2 (GEMM first, then gather of p-half fused with segmax) ---
    k_gemm2<<<NP / 64, 256, 0, stream>>>(H1, Wpk2, PQ);
    k_final<<<NN / 4, 256, 0, stream>>>(off, csr, PQ, b2, batch, om);

    k_decode<<<(NG * 64 + 255) / 256, 256, 0, stream>>>(om, out);
}

// Round 4
// 418.547 us; speedup vs baseline: 11.0450x; 1.2640x over previous
//
#include <hip/hip_runtime.h>
#include <cstdint>

#define NN 100000      // nodes
#define NE 1600000     // edges
#define NG 512         // graphs
#define NP 100032      // NN padded to 64*1563
#define NBLK 391       // ceil(NN/256) for scan kernels
#define NSLICE 12500   // NN / 8  (per-XCD dst slice)
#define VOCAB 10000

typedef unsigned short u16;
typedef u16    u16x8  __attribute__((ext_vector_type(8)));
typedef __bf16 bf16x8 __attribute__((ext_vector_type(8)));
typedef float  f32x4  __attribute__((ext_vector_type(4)));

__device__ __forceinline__ u16 f2bf(float f) {  // RNE, inputs are normal floats
    unsigned u = __float_as_uint(f);
    unsigned r = ((u >> 16) & 1u) + 0x7FFFu;
    return (u16)((u + r) >> 16);
}
__device__ __forceinline__ float bf2f(u16 h) {
    return __uint_as_float(((unsigned)h) << 16);
}

// monotone float->uint encoding so unsigned atomicMax == float max
__device__ __forceinline__ unsigned encF(float f) {
    unsigned s = __float_as_uint(f);
    return (s & 0x80000000u) ? ~s : (s | 0x80000000u);
}
__device__ __forceinline__ float decF(unsigned m) {
    unsigned s = (m & 0x80000000u) ? (m ^ 0x80000000u) : ~m;
    return __uint_as_float(s);
}

__global__ void k_init_outmax(unsigned* __restrict__ om) {
    int i = blockIdx.x * blockDim.x + threadIdx.x;
    if (i < NG * 64) om[i] = 0x007FFFFFu;  // encF(-inf)
}

// fp32 embedding table -> bf16 (1.25 MB, L2-resident everywhere)
__global__ void k_embB(const float* __restrict__ emb, u16* __restrict__ embB) {
    int i = blockIdx.x * blockDim.x + threadIdx.x;
    if (i < VOCAB * 64) embB[i] = f2bf(emb[i]);
}

// x_i half of A1 (cols 64..127) from bf16 table
__global__ void k_embed(const int* __restrict__ x, const u16* __restrict__ embB,
                        u16* __restrict__ A1) {
    int idx = blockIdx.x * blockDim.x + threadIdx.x;
    if (idx >= NN * 64) return;
    int node = idx >> 6, d = idx & 63;
    A1[node * 128 + 64 + d] = embB[x[node] * 64 + d];
}

// ---- CSR construction, XCD-partitioned: group g = blockIdx&7 owns dst slice g ----
__global__ __launch_bounds__(256) void k_count(const int* __restrict__ ei,
                                               int* __restrict__ degi) {
    int g = blockIdx.x & 7, bi = blockIdx.x >> 3;  // 128 blocks per group
    int lo = g * NSLICE;
    const int chunk = NE / 128;  // 12500
    int e0 = bi * chunk, e1 = e0 + chunk;
    for (int e = e0 + threadIdx.x; e < e1; e += 256) {
        int dst = ei[NE + e];
        if ((unsigned)(dst - lo) < (unsigned)NSLICE) atomicAdd(&degi[dst], 1);
    }
}

__global__ void k_blocksum(const int* __restrict__ degi, int* __restrict__ partial) {
    __shared__ int s[256];
    int i = blockIdx.x * 256 + threadIdx.x;
    s[threadIdx.x] = (i < NN) ? degi[i] : 0;
    __syncthreads();
    for (int d = 128; d > 0; d >>= 1) {
        if (threadIdx.x < d) s[threadIdx.x] += s[threadIdx.x + d];
        __syncthreads();
    }
    if (threadIdx.x == 0) partial[blockIdx.x] = s[0];
}

__global__ __launch_bounds__(512) void k_scanpart(const int* __restrict__ partial,
                                                  int* __restrict__ bases) {
    __shared__ int s[512];
    int t = threadIdx.x;
    s[t] = (t < NBLK) ? partial[t] : 0;
    __syncthreads();
    for (int d = 1; d < 512; d <<= 1) {
        int v = (t >= d) ? s[t - d] : 0;
        __syncthreads();
        s[t] += v;
        __syncthreads();
    }
    if (t < NBLK) bases[t] = (t == 0) ? 0 : s[t - 1];
}

__global__ void k_offsets(const int* __restrict__ degi, const int* __restrict__ bases,
                          int* __restrict__ off) {
    __shared__ int s[256];
    int t = threadIdx.x, i = blockIdx.x * 256 + t;
    int d = (i < NN) ? degi[i] : 0;
    s[t] = d;
    __syncthreads();
    for (int dd = 1; dd < 256; dd <<= 1) {
        int v = (t >= dd) ? s[t - dd] : 0;
        __syncthreads();
        s[t] += v;
        __syncthreads();
    }
    if (i < NN) off[i] = bases[blockIdx.x] + s[t] - d;  // exclusive
    if (blockIdx.x == gridDim.x - 1 && t == 255) off[NN] = NE;
}

// csr entry = src | (x[src] << 17): src<2^17, x<2^14
__global__ __launch_bounds__(256) void k_fill(const int* __restrict__ ei,
                                              const int* __restrict__ x,
                                              const int* __restrict__ off,
                                              int* __restrict__ cur,
                                              int* __restrict__ csr) {
    int g = blockIdx.x & 7, bi = blockIdx.x >> 3;
    int lo = g * NSLICE;
    const int chunk = NE / 128;
    int e0 = bi * chunk, e1 = e0 + chunk;
    for (int e = e0 + threadIdx.x; e < e1; e += 256) {
        int dst = ei[NE + e];
        if ((unsigned)(dst - lo) < (unsigned)NSLICE) {
            int src = ei[e];
            int pos = off[dst] + atomicAdd(&cur[dst], 1);
            csr[pos] = src | (x[src] << 17);
        }
    }
}

// ---- weight prep: fp32 concat -> bf16 packed in B-fragment order ----
__global__ void k_prepW(const float* __restrict__ Wa, const float* __restrict__ Wb,
                        int mode, u16* __restrict__ Wpk) {
    int idx = blockIdx.x * blockDim.x + threadIdx.x;  // 0..2047
    if (idx >= 2048) return;
    int fid = idx >> 6, lane = idx & 63;
    int cT = fid >> 2, ks = fid & 3;
    int quad = lane >> 4, l16 = lane & 15;
    int n = cT * 16 + l16;
    u16x8 v;
    #pragma unroll
    for (int j = 0; j < 8; ++j) {
        int k = ks * 32 + quad * 8 + j;
        float f = (mode == 0) ? (k < 64 ? Wa[k * 128 + n] : Wb[(k - 64) * 128 + n])
                              : (n < 64 ? Wa[k * 64 + n] : Wb[k * 64 + (n - 64)]);
        v[j] = f2bf(f);
    }
    *(u16x8*)(Wpk + idx * 8) = v;
}

// ---- gather-mean of emb[x[src]] into cols 0..63 of A1 ----
__global__ __launch_bounds__(256) void k_gather1(const int* __restrict__ off,
                                                 const int* __restrict__ csr,
                                                 const u16* __restrict__ embB,
                                                 u16* __restrict__ A1) {
    int wid = (blockIdx.x * blockDim.x + threadIdx.x) >> 6;  // node
    int lane = threadIdx.x & 63;
    if (wid >= NN) return;
    int beg = off[wid], end = off[wid + 1];
    float acc = 0.0f;
    for (int base = beg; base < end; base += 64) {
        int n = min(64, end - base);
        int s = (lane < n) ? csr[base + lane] : 0;
        int j = 0;
        for (; j + 1 < n; j += 2) {
            int p0 = __builtin_amdgcn_readlane(s, j);
            int p1 = __builtin_amdgcn_readlane(s, j + 1);
            float v0 = bf2f(embB[(p0 >> 17) * 64 + lane]);
            float v1 = bf2f(embB[(p1 >> 17) * 64 + lane]);
            acc += v0 + v1;
        }
        if (j < n) {
            int p0 = __builtin_amdgcn_readlane(s, j);
            acc += bf2f(embB[(p0 >> 17) * 64 + lane]);
        }
    }
    A1[wid * 128 + lane] = f2bf(acc / fmaxf((float)(end - beg), 1.0f));
}

// ---- GEMM1: H1 = relu(A1[NPx128] @ Wpk1[128x128] + b1), bf16 out ----
__global__ __launch_bounds__(256) void k_gemm1(const u16* __restrict__ A1,
                                               const u16* __restrict__ Wpk,
                                               const float* __restrict__ b1,
                                               u16* __restrict__ H1) {
    int w = threadIdx.x >> 6, lane = threadIdx.x & 63;
    int quad = lane >> 4, l16 = lane & 15;
    u16x8 bfr[2][4];
    #pragma unroll
    for (int ct = 0; ct < 2; ++ct)
        #pragma unroll
        for (int ks = 0; ks < 4; ++ks) {
            int fid = (w * 2 + ct) * 4 + ks;
            bfr[ct][ks] = *(const u16x8*)(Wpk + (fid * 64 + lane) * 8);
        }
    int r0 = blockIdx.x * 64;
    #pragma unroll
    for (int rt = 0; rt < 4; ++rt) {
        int row = r0 + rt * 16 + l16;
        u16x8 a[4];
        #pragma unroll
        for (int ks = 0; ks < 4; ++ks)
            a[ks] = *(const u16x8*)(A1 + row * 128 + ks * 32 + quad * 8);
        #pragma unroll
        for (int ct = 0; ct < 2; ++ct) {
            f32x4 acc = {0.f, 0.f, 0.f, 0.f};
            #pragma unroll
            for (int ks = 0; ks < 4; ++ks)
                acc = __builtin_amdgcn_mfma_f32_16x16x32_bf16(
                    __builtin_bit_cast(bf16x8, a[ks]),
                    __builtin_bit_cast(bf16x8, bfr[ct][ks]), acc, 0, 0, 0);
            int col = w * 32 + ct * 16 + l16;
            float bias = b1[col];
            int gr = r0 + rt * 16 + quad * 4;
            #pragma unroll
            for (int reg = 0; reg < 4; ++reg)
                H1[(gr + reg) * 128 + col] = f2bf(fmaxf(acc[reg] + bias, 0.f));
        }
    }
}

// ---- GEMM2: PQ = H1[NPx128] @ Wpk2[128x128], bf16 out (p=cols 0..63, q=64..127) ----
__global__ __launch_bounds__(256) void k_gemm2(const u16* __restrict__ H1,
                                               const u16* __restrict__ Wpk,
                                               u16* __restrict__ PQ) {
    int w = threadIdx.x >> 6, lane = threadIdx.x & 63;
    int quad = lane >> 4, l16 = lane & 15;
    u16x8 bfr[2][4];
    #pragma unroll
    for (int ct = 0; ct < 2; ++ct)
        #pragma unroll
        for (int ks = 0; ks < 4; ++ks) {
            int fid = (w * 2 + ct) * 4 + ks;
            bfr[ct][ks] = *(const u16x8*)(Wpk + (fid * 64 + lane) * 8);
        }
    int r0 = blockIdx.x * 64;
    #pragma unroll
    for (int rt = 0; rt < 4; ++rt) {
        int row = r0 + rt * 16 + l16;
        u16x8 a[4];
        #pragma unroll
        for (int ks = 0; ks < 4; ++ks)
            a[ks] = *(const u16x8*)(H1 + row * 128 + ks * 32 + quad * 8);
        #pragma unroll
        for (int ct = 0; ct < 2; ++ct) {
            f32x4 acc = {0.f, 0.f, 0.f, 0.f};
            #pragma unroll
            for (int ks = 0; ks < 4; ++ks)
                acc = __builtin_amdgcn_mfma_f32_16x16x32_bf16(
                    __builtin_bit_cast(bf16x8, a[ks]),
                    __builtin_bit_cast(bf16x8, bfr[ct][ks]), acc, 0, 0, 0);
            int col = w * 32 + ct * 16 + l16;
            int gr = r0 + rt * 16 + quad * 4;
            #pragma unroll
            for (int reg = 0; reg < 4; ++reg)
                PQ[(gr + reg) * 128 + col] = f2bf(acc[reg]);
        }
    }
}

// ---- final: h2 = mean_agg(p) + b2 + q, segment-max into om ----
__global__ __launch_bounds__(256) void k_final(const int* __restrict__ off,
                                               const int* __restrict__ csr,
                                               const u16* __restrict__ PQ,
                                               const float* __restrict__ b2,
                                               const int* __restrict__ batch,
                                               unsigned* __restrict__ om) {
    __shared__ float sR[4][64];
    __shared__ int sG[4];
    int wv = threadIdx.x >> 6, lane = threadIdx.x & 63;
    int node = blockIdx.x * 4 + wv;  // NN % 4 == 0, always valid
    int beg = off[node], end = off[node + 1];
    float acc = 0.0f;
    for (int base = beg; base < end; base += 64) {
        int n = min(64, end - base);
        int s = (lane < n) ? csr[base + lane] : 0;
        int j = 0;
        for (; j + 1 < n; j += 2) {
            int p0 = __builtin_amdgcn_readlane(s, j) & 0x1FFFF;
            int p1 = __builtin_amdgcn_readlane(s, j + 1) & 0x1FFFF;
            float v0 = bf2f(PQ[p0 * 128 + lane]);
            float v1 = bf2f(PQ[p1 * 128 + lane]);
            acc += v0 + v1;
        }
        if (j < n) {
            int p0 = __builtin_amdgcn_readlane(s, j) & 0x1FFFF;
            acc += bf2f(PQ[p0 * 128 + lane]);
        }
    }
    float r = acc / fmaxf((float)(end - beg), 1.0f) + b2[lane]
            + bf2f(PQ[node * 128 + 64 + lane]);
    int g = batch[node];
    sR[wv][lane] = r;
    if (lane == 0) sG[wv] = g;
    __syncthreads();
    bool leader = (wv == 0) || (sG[wv - 1] != g);
    if (leader) {
        float m = r;
        for (int u = wv + 1; u < 4 && sG[u] == g; ++u) m = fmaxf(m, sR[u][lane]);
        atomicMax(&om[g * 64 + lane], encF(m));
    }
}

__global__ void k_decode(const unsigned* __restrict__ om, float* __restrict__ out) {
    int i = blockIdx.x * blockDim.x + threadIdx.x;
    if (i < NG * 64) out[i] = decF(om[i]);
}

extern "C" void kernel_launch(void* const* d_in, const int* in_sizes, int n_in,
                              void* d_out, int out_size, void* d_ws, size_t ws_size,
                              hipStream_t stream) {
    const int*   x     = (const int*)d_in[0];
    const int*   ei    = (const int*)d_in[1];   // [2, NE] flat: src | dst
    const int*   batch = (const int*)d_in[2];
    // d_in[3] = edge_attr, unused by SAGEConv
    const float* emb   = (const float*)d_in[4];
    const float* W1l   = (const float*)d_in[5];
    const float* b1    = (const float*)d_in[6];
    const float* W1r   = (const float*)d_in[7];
    const float* W2l   = (const float*)d_in[8];
    const float* b2    = (const float*)d_in[9];
    const float* W2r   = (const float*)d_in[10];
    float* out = (float*)d_out;

    // workspace layout (bytes). bf16 tables are NP x 128.
    char* p = (char*)d_ws;
    u16* A1   = (u16*)p;               p += (size_t)NP * 128 * 2;  // [agg1 | h0]
    u16* H1   = (u16*)p;               p += (size_t)NP * 128 * 2;
    u16* PQ   = (u16*)p;               p += (size_t)NP * 128 * 2;  // [p | q]
    int* csr  = (int*)p;               p += (size_t)NE * 4;
    int* off  = (int*)p;               p += (size_t)(NN + 1) * 4;
    int* degi = (int*)p;               p += (size_t)NN * 4;        // also fill cursor
    int* part = (int*)p;               p += 512 * 4;
    int* base = (int*)p;               p += 512 * 4;
    u16* Wpk1 = (u16*)p;               p += 16384 * 2;
    u16* Wpk2 = (u16*)p;               p += 16384 * 2;
    u16* embB = (u16*)p;               p += (size_t)VOCAB * 64 * 2;
    unsigned* om = (unsigned*)p;

    // --- CSR build (XCD-partitioned count/fill) ---
    hipMemsetAsync(degi, 0, sizeof(int) * NN, stream);
    k_count<<<1024, 256, 0, stream>>>(ei, degi);
    k_blocksum<<<NBLK, 256, 0, stream>>>(degi, part);
    k_scanpart<<<1, 512, 0, stream>>>(part, base);
    k_offsets<<<NBLK, 256, 0, stream>>>(degi, base, off);
    hipMemsetAsync(degi, 0, sizeof(int) * NN, stream);  // reuse as cursor
    k_fill<<<1024, 256, 0, stream>>>(ei, x, off, degi, csr);

    // --- weight/emb prep + init ---
    k_embB<<<(VOCAB * 64 + 255) / 256, 256, 0, stream>>>(emb, embB);
    k_prepW<<<8, 256, 0, stream>>>(W1l, W1r, 0, Wpk1);  // vertical stack [W1l;W1r]
    k_prepW<<<8, 256, 0, stream>>>(W2l, W2r, 1, Wpk2);  // horizontal [W2l|W2r]
    k_init_outmax<<<(NG * 64 + 255) / 256, 256, 0, stream>>>(om);

    // --- layer 1 ---
    k_embed<<<(NN * 64 + 255) / 256, 256, 0, stream>>>(x, embB, A1);
    k_gather1<<<(NN * 64 + 255) / 256, 256, 0, stream>>>(off, csr, embB, A1);
    k_gemm1<<<NP / 64, 256, 0, stream>>>(A1, Wpk1, b1, H1);

    // --- layer 2 (GEMM first, then gather of p-half fused with segmax) ---
    k_gemm2<<<NP / 64, 256, 0, stream>>>(H1, Wpk2, PQ);
    k_final<<<NN / 4, 256, 0, stream>>>(off, csr, PQ, b2, batch, om);

    k_decode<<<(NG * 64 + 255) / 256, 256, 0, stream>>>(om, out);
}